// Round 7
// baseline (19844.859 us; speedup 1.0000x reference)
//
#include <hip/hip_runtime.h>
#include <stdint.h>
#include <math.h>

// Problem constants (match reference)
#define BB 128
#define NN 2048
#define DD 2
#define ROWLEN (2 + NN * DD + 5)   // 4103
#define SIGMA_C 0.001f
#define HALF_CNT 262144u           // B*N*D / 2

#define TPB 128                    // threads per block (2 waves)

// SSA vector types (subscripts -> insert/extractelement, never allocas).
typedef float v8f  __attribute__((ext_vector_type(8)));
typedef float v16f __attribute__((ext_vector_type(16)));
typedef float v32f __attribute__((ext_vector_type(32)));

// elu derivative from elu output: d = (z>0) ? 1 : exp(z); for z<=0,
// h = exp(z)-1  =>  d = h+1 (<=1 ulp). h>0 <=> z>0 (monotone).
#define DFROMH(h) ((h) > 0.0f ? 1.0f : (h) + 1.0f)

// Phase fence: keep the scheduler from hoisting next-phase weight loads into
// the current phase (R6 evidence: hoisting inflates pressure ~20+ regs ->
// marginal scratch spill -> uncached-scratch HBM round-trips dominate).
#define PHASE_FENCE() __builtin_amdgcn_sched_barrier(0)

__device__ __forceinline__ uint32_t rotl32(uint32_t v, uint32_t r) {
  return (v << r) | (v >> (32u - r));
}

// JAX threefry2x32 (20 rounds), matches jax/_src/prng.py
__device__ __forceinline__ void tf2x32(uint32_t k0, uint32_t k1,
                                       uint32_t x0, uint32_t x1,
                                       uint32_t& o0, uint32_t& o1) {
  uint32_t k2 = k0 ^ k1 ^ 0x1BD11BDAu;
  x0 += k0; x1 += k1;
#define TF_R(r) { x0 += x1; x1 = rotl32(x1, r); x1 ^= x0; }
  TF_R(13) TF_R(15) TF_R(26) TF_R(6)   x0 += k1; x1 += k2 + 1u;
  TF_R(17) TF_R(29) TF_R(16) TF_R(24)  x0 += k2; x1 += k0 + 2u;
  TF_R(13) TF_R(15) TF_R(26) TF_R(6)   x0 += k0; x1 += k1 + 3u;
  TF_R(17) TF_R(29) TF_R(16) TF_R(24)  x0 += k1; x1 += k2 + 4u;
  TF_R(13) TF_R(15) TF_R(26) TF_R(6)   x0 += k2; x1 += k0 + 5u;
#undef TF_R
  o0 = x0; o1 = x1;
}

// XLA f32 ErfInv (Giles 2012 polynomial) — what lax.erf_inv lowers to
__device__ __forceinline__ float erfinv_f32(float x) {
  float w = -log1pf(-(x * x));
  float p;
  if (w < 5.0f) {
    w = w - 2.5f;
    p = 2.81022636e-08f;
    p = fmaf(p, w, 3.43273939e-07f);
    p = fmaf(p, w, -3.5233877e-06f);
    p = fmaf(p, w, -4.39150654e-06f);
    p = fmaf(p, w, 0.00021858087f);
    p = fmaf(p, w, -0.00125372503f);
    p = fmaf(p, w, -0.00417768164f);
    p = fmaf(p, w, 0.246640727f);
    p = fmaf(p, w, 1.50140941f);
  } else {
    w = sqrtf(w) - 3.0f;
    p = -0.000200214257f;
    p = fmaf(p, w, 0.000100950558f);
    p = fmaf(p, w, 0.00134934322f);
    p = fmaf(p, w, -0.00367342844f);
    p = fmaf(p, w, 0.00573950773f);
    p = fmaf(p, w, -0.0076224613f);
    p = fmaf(p, w, 0.00943887047f);
    p = fmaf(p, w, 1.00167406f);
    p = fmaf(p, w, 2.83297682f);
  }
  return p * x;
}

// jax.random.normal for one flat element index f under key (k0,k1)
__device__ __forceinline__ float jax_normal_elem(uint32_t k0, uint32_t k1,
                                                 uint32_t f) {
  uint32_t o0, o1, bits;
  if (f < HALF_CNT) {
    tf2x32(k0, k1, f, f + HALF_CNT, o0, o1);
    bits = o0;
  } else {
    tf2x32(k0, k1, f - HALF_CNT, f, o0, o1);
    bits = o1;
  }
  float u01 = __uint_as_float((bits >> 9) | 0x3f800000u) - 1.0f;
  const float lo = -0.99999994f;           // nextafter(-1, 0) in f32
  float v = fmaxf(lo, fmaf(u01, 2.0f, lo));
  return 1.41421356237309515f * erfinv_f32(v);
}

// LDS stash: h2 (32) + h3 (32) + h1 (16) = 80 floats/thread.
// 80 * 128 * 4 B = 40 KB/block -> 4 blocks/CU (2 waves/EU).
// Layout [slot][tid]: lane-consecutive -> 2-way bank aliasing only (free).
// Private per-thread columns: no barriers.
#define SLOT_H2 0
#define SLOT_H3 32
#define SLOT_H1 64
#define LDS_FLOATS (80 * TPB)

// R1-R6 lesson: RA grants ~84-104 VGPRs regardless of hints; ANY spill goes
// through (effectively uncached) scratch to HBM. Zero-spill requires
// structural peak well under the grant. This version: fwd peak ~56
// (h1 + 8-block h2 + z3 accs), bwd peak ~50 (g4 + streamed a3 column-walk
// into a2) — never two full 32-vectors plus a third alive.
__global__ __launch_bounds__(TPB, 2) void phinn_kernel(
    const float* __restrict__ x,
    const float* __restrict__ W1, const float* __restrict__ b1,
    const float* __restrict__ W2, const float* __restrict__ b2,
    const float* __restrict__ W3, const float* __restrict__ b3,
    const float* __restrict__ W4, const float* __restrict__ b4,
    const float* __restrict__ W5, const float* __restrict__ b5,
    const float* __restrict__ Wt,
    const float* __restrict__ dtp, const int* __restrict__ nstepsp,
    float* __restrict__ out) {
  __shared__ float sh[LDS_FLOATS];

  const int tx = threadIdx.x;
  const int tid = blockIdx.x * TPB + tx;   // 0 .. B*N-1
  const int bidx = tid >> 11;               // / N
  const int nidx = tid & (NN - 1);

  const float dt = dtp[0];
  const int nsteps = nstepsp[0];
  const float sqdt = sqrtf(dt);

  const float* xr = x + (size_t)bidx * ROWLEN;
  float t = xr[0];
  float y0 = xr[2 + nidx * 2 + 0];
  float y1 = xr[2 + nidx * 2 + 1];
  const float tcrit = xr[2 + NN * DD + 0];
  const float sp0 = xr[2 + NN * DD + 1];
  const float sp1 = xr[2 + NN * DD + 2];
  const float sq0 = xr[2 + NN * DD + 3];
  const float sq1 = xr[2 + NN * DD + 4];

  // Wt is (D, NSIG) row-major; tilt[d] = sum_s signals[s] * Wt[d][s]
  const float wt00 = Wt[0], wt01 = Wt[1], wt10 = Wt[2], wt11 = Wt[3];

  const uint32_t f0 = (uint32_t)(tid << 1);  // flat idx of component 0

#pragma unroll 1
  for (int i = 0; i < nsteps; ++i) {
    // per-step key: fold_in(key(42), i) = threefry((0,42), (0,i)); i uniform
    uint32_t k0, k1;
    tf2x32(0u, 42u, 0u, (uint32_t)i, k0, k1);

    // ---- layer 1: 2 -> 16 (rows of W1); stash h1 ----
    v16f h1;
#pragma unroll
    for (int j = 0; j < 16; ++j) {
      float z = fmaf(W1[2 * j + 0], y0, fmaf(W1[2 * j + 1], y1, b1[j]));
      float h = z > 0.0f ? z : (__expf(z) - 1.0f);
      h1[j] = h;
      sh[(SLOT_H1 + j) * TPB + tx] = h;
    }
    PHASE_FENCE();

    // ---- layer 2 (16->32) fused with z3 accumulation (32), 8-blocks ----
    // z3[jj]: b3 first, then k ascending — bit-identical to R4/R6.
    v32f z3;
#pragma unroll
    for (int jb = 0; jb < 4; ++jb) {
      v8f h2b;
#pragma unroll
      for (int u = 0; u < 8; ++u) {
        const int j = jb * 8 + u;
        float z = b2[j];
#pragma unroll
        for (int k = 0; k < 16; ++k) z = fmaf(W2[16 * j + k], h1[k], z);
        float h = z > 0.0f ? z : (__expf(z) - 1.0f);
        h2b[u] = h;
        sh[(SLOT_H2 + j) * TPB + tx] = h;
      }
#pragma unroll
      for (int jj = 0; jj < 32; ++jj) {
        float acc = (jb == 0) ? b3[jj] : z3[jj];
#pragma unroll
        for (int u = 0; u < 8; ++u)
          acc = fmaf(W3[32 * jj + jb * 8 + u], h2b[u], acc);
        z3[jj] = acc;
      }
    }
    PHASE_FENCE();

    // ---- layer 3 activate fused with z4 accumulation (16), 8-blocks ----
    v16f z4;
#pragma unroll
    for (int jb = 0; jb < 4; ++jb) {
      v8f h3b;
#pragma unroll
      for (int u = 0; u < 8; ++u) {
        const int j = jb * 8 + u;
        float zz = z3[j];
        float h = zz > 0.0f ? zz : (__expf(zz) - 1.0f);
        h3b[u] = h;
        sh[(SLOT_H3 + j) * TPB + tx] = h;
      }
#pragma unroll
      for (int ii = 0; ii < 16; ++ii) {
        float acc = (jb == 0) ? b4[ii] : z4[ii];
#pragma unroll
        for (int u = 0; u < 8; ++u)
          acc = fmaf(W4[32 * ii + jb * 8 + u], h3b[u], acc);
        z4[ii] = acc;
      }
    }
    PHASE_FENCE();

    // ---- layer 4 activate + layer 5 + softplus' + g4 ----
    v16f h4;
#pragma unroll
    for (int j = 0; j < 16; ++j) {
      float zz = z4[j];
      h4[j] = zz > 0.0f ? zz : (__expf(zz) - 1.0f);
    }
    float z5 = b5[0];
#pragma unroll
    for (int k = 0; k < 16; ++k) z5 = fmaf(W5[k], h4[k], z5);
    float g5 = 1.0f / (1.0f + __expf(-z5));  // d softplus = sigmoid

    v16f g4;
#pragma unroll
    for (int k = 0; k < 16; ++k) g4[k] = W5[k] * g5 * DFROMH(h4[k]);
    PHASE_FENCE();

    // ---- backward: stream a3 column-walk directly into a2 ----
    // a3k transient: column k of W4 dotted with g4 (j ascending, same order
    // as R6); g3k = a3k*d3k immediately consumed into a2 accumulation
    // (k ascending = R6's j ascending, same init at k==0). Peak: g4+a2 = 48.
    v32f a2;
#pragma unroll
    for (int k = 0; k < 32; ++k) {
      float a3k = 0.0f;
#pragma unroll
      for (int j = 0; j < 16; ++j) {
        float w = W4[32 * j + k];
        a3k = (j == 0) ? w * g4[0] : fmaf(w, g4[j], a3k);
      }
      float g3k = a3k * DFROMH(sh[(SLOT_H3 + k) * TPB + tx]);
#pragma unroll
      for (int kk = 0; kk < 32; ++kk) {
        float w = W3[32 * k + kk];
        a2[kk] = (k == 0) ? w * g3k : fmaf(w, g3k, a2[kk]);
      }
    }
    PHASE_FENCE();

    // g2 streamed into a1 (k ascending; same order/init as R6)
    v16f a1;
#pragma unroll
    for (int k = 0; k < 32; ++k) {
      float g2k = a2[k] * DFROMH(sh[(SLOT_H2 + k) * TPB + tx]);
#pragma unroll
      for (int kk = 0; kk < 16; ++kk) {
        float w = W2[16 * k + kk];
        a1[kk] = (k == 0) ? w * g2k : fmaf(w, g2k, a1[kk]);
      }
    }
    // gy = W1^T (a1 * d1)
    float gy0 = 0.0f, gy1 = 0.0f;
#pragma unroll
    for (int j = 0; j < 16; ++j) {
      float g1j = a1[j] * DFROMH(sh[(SLOT_H1 + j) * TPB + tx]);
      gy0 = fmaf(W1[2 * j + 0], g1j, gy0);
      gy1 = fmaf(W1[2 * j + 1], g1j, gy1);
    }
    PHASE_FENCE();

    // ---- tilt ----
    bool pre = t < tcrit;
    float s0 = pre ? sp0 : sq0;
    float s1 = pre ? sp1 : sq1;
    float tilt0 = fmaf(s0, wt00, s1 * wt01);
    float tilt1 = fmaf(s0, wt10, s1 * wt11);

    // ---- noise (exact JAX threefry normal) ----
    float nz0 = jax_normal_elem(k0, k1, f0);
    float nz1 = jax_normal_elem(k0, k1, f0 + 1u);

    // ---- Euler-Maruyama update ----
    float drift0 = -(gy0 + tilt0);
    float drift1 = -(gy1 + tilt1);
    y0 = y0 + drift0 * dt + SIGMA_C * (nz0 * sqdt);
    y1 = y1 + drift1 * dt + SIGMA_C * (nz1 * sqdt);
    t += dt;
  }

  out[(size_t)tid * 2 + 0] = y0;
  out[(size_t)tid * 2 + 1] = y1;
}

extern "C" void kernel_launch(void* const* d_in, const int* in_sizes, int n_in,
                              void* d_out, int out_size, void* d_ws,
                              size_t ws_size, hipStream_t stream) {
  const float* x  = (const float*)d_in[0];
  const float* W1 = (const float*)d_in[1];
  const float* b1 = (const float*)d_in[2];
  const float* W2 = (const float*)d_in[3];
  const float* b2 = (const float*)d_in[4];
  const float* W3 = (const float*)d_in[5];
  const float* b3 = (const float*)d_in[6];
  const float* W4 = (const float*)d_in[7];
  const float* b4 = (const float*)d_in[8];
  const float* W5 = (const float*)d_in[9];
  const float* b5 = (const float*)d_in[10];
  const float* Wt = (const float*)d_in[11];
  const float* dt = (const float*)d_in[12];
  const int* nsteps = (const int*)d_in[13];
  float* out = (float*)d_out;

  dim3 grid((BB * NN) / TPB);
  dim3 block(TPB);
  hipLaunchKernelGGL(phinn_kernel, grid, block, 0, stream,
                     x, W1, b1, W2, b2, W3, b3, W4, b4, W5, b5, Wt, dt, nsteps,
                     out);
}

// Round 8
// 9291.453 us; speedup vs baseline: 2.1358x; 2.1358x over previous
//
#include <hip/hip_runtime.h>
#include <stdint.h>
#include <math.h>

// Problem constants (match reference)
#define BB 128
#define NN 2048
#define DD 2
#define ROWLEN (2 + NN * DD + 5)   // 4103
#define SIGMA_C 0.001f
#define HALF_CNT 262144u           // B*N*D / 2

#define TPB 128                    // threads per block (2 waves)

// R1-R7 lessons:
//  - float arrays  -> allocas -> scratch (SROA runs before unroll): R1/R2.
//  - ext_vector(32/16) -> single SSA values needing 32/16 CONTIGUOUS VGPRs;
//    allocator can't pack several rigid tuples -> spills whole tuples even
//    at low total demand (R3-R7: 2.7-4.3 dwords/thread-step stored, FETCH
//    1-2 GB from L2-thrashed weight stream).
//  - sched_barrier(0) extends live ranges -> +24 VGPR, +60% spill (R7).
// Fix: EVERY value is an individually named scalar float (macro-expanded).
// Pure SSA, spill granularity 1 reg, no contiguity constraints, no fences.

#define ELU(z) ((z) > 0.0f ? (z) : (__expf(z) - 1.0f))
// elu' from elu output: d = (z>0) ? 1 : exp(z) = h+1 for z<=0 (<=1 ulp)
#define DFROMH(h) ((h) > 0.0f ? 1.0f : (h) + 1.0f)

__device__ __forceinline__ uint32_t rotl32(uint32_t v, uint32_t r) {
  return (v << r) | (v >> (32u - r));
}

// JAX threefry2x32 (20 rounds), matches jax/_src/prng.py
__device__ __forceinline__ void tf2x32(uint32_t k0, uint32_t k1,
                                       uint32_t x0, uint32_t x1,
                                       uint32_t& o0, uint32_t& o1) {
  uint32_t k2 = k0 ^ k1 ^ 0x1BD11BDAu;
  x0 += k0; x1 += k1;
#define TF_R(r) { x0 += x1; x1 = rotl32(x1, r); x1 ^= x0; }
  TF_R(13) TF_R(15) TF_R(26) TF_R(6)   x0 += k1; x1 += k2 + 1u;
  TF_R(17) TF_R(29) TF_R(16) TF_R(24)  x0 += k2; x1 += k0 + 2u;
  TF_R(13) TF_R(15) TF_R(26) TF_R(6)   x0 += k0; x1 += k1 + 3u;
  TF_R(17) TF_R(29) TF_R(16) TF_R(24)  x0 += k1; x1 += k2 + 4u;
  TF_R(13) TF_R(15) TF_R(26) TF_R(6)   x0 += k2; x1 += k0 + 5u;
#undef TF_R
  o0 = x0; o1 = x1;
}

// XLA f32 ErfInv (Giles 2012 polynomial)
__device__ __forceinline__ float erfinv_f32(float x) {
  float w = -log1pf(-(x * x));
  float p;
  if (w < 5.0f) {
    w = w - 2.5f;
    p = 2.81022636e-08f;
    p = fmaf(p, w, 3.43273939e-07f);
    p = fmaf(p, w, -3.5233877e-06f);
    p = fmaf(p, w, -4.39150654e-06f);
    p = fmaf(p, w, 0.00021858087f);
    p = fmaf(p, w, -0.00125372503f);
    p = fmaf(p, w, -0.00417768164f);
    p = fmaf(p, w, 0.246640727f);
    p = fmaf(p, w, 1.50140941f);
  } else {
    w = sqrtf(w) - 3.0f;
    p = -0.000200214257f;
    p = fmaf(p, w, 0.000100950558f);
    p = fmaf(p, w, 0.00134934322f);
    p = fmaf(p, w, -0.00367342844f);
    p = fmaf(p, w, 0.00573950773f);
    p = fmaf(p, w, -0.0076224613f);
    p = fmaf(p, w, 0.00943887047f);
    p = fmaf(p, w, 1.00167406f);
    p = fmaf(p, w, 2.83297682f);
  }
  return p * x;
}

// jax.random.normal for one flat element index f under key (k0,k1)
__device__ __forceinline__ float jax_normal_elem(uint32_t k0, uint32_t k1,
                                                 uint32_t f) {
  uint32_t o0, o1, bits;
  if (f < HALF_CNT) {
    tf2x32(k0, k1, f, f + HALF_CNT, o0, o1);
    bits = o0;
  } else {
    tf2x32(k0, k1, f - HALF_CNT, f, o0, o1);
    bits = o1;
  }
  float u01 = __uint_as_float((bits >> 9) | 0x3f800000u) - 1.0f;
  const float lo = -0.99999994f;           // nextafter(-1, 0) in f32
  float v = fmaxf(lo, fmaf(u01, 2.0f, lo));
  return 1.41421356237309515f * erfinv_f32(v);
}

// ---- repetition helpers ----
#define REP16(M) M(0) M(1) M(2) M(3) M(4) M(5) M(6) M(7) M(8) M(9) M(10) M(11) M(12) M(13) M(14) M(15)
#define REP32(M) REP16(M) M(16) M(17) M(18) M(19) M(20) M(21) M(22) M(23) M(24) M(25) M(26) M(27) M(28) M(29) M(30) M(31)
#define REP16_2(M,a) M(0,a) M(1,a) M(2,a) M(3,a) M(4,a) M(5,a) M(6,a) M(7,a) M(8,a) M(9,a) M(10,a) M(11,a) M(12,a) M(13,a) M(14,a) M(15,a)
#define REP32_2(M,a) REP16_2(M,a) M(16,a) M(17,a) M(18,a) M(19,a) M(20,a) M(21,a) M(22,a) M(23,a) M(24,a) M(25,a) M(26,a) M(27,a) M(28,a) M(29,a) M(30,a) M(31,a)

// LDS stash: h2 [0..31], h3 [32..63], h1 [64..79] -> 80 floats/thread.
// 80 * 128 * 4 B = 40 KB/block -> 4 blocks/CU. [slot][tid] layout:
// lane-consecutive (2-way bank aliasing = free). Private columns: no barriers.
#define SLOT_H2 0
#define SLOT_H3 32
#define SLOT_H1 64
#define LDS_FLOATS (80 * TPB)

// ---- per-step macro bodies (all indices compile-time literals) ----
// declarations
#define DH1(j) float h1_##j;
#define DZ3(j) float z3_##j;
#define DZ4(j) float z4_##j;
#define DA2(j) float a2_##j;
#define DA1(j) float a1_##j;

// layer 1 unit: z = fmaf(W1[2j], y0, fmaf(W1[2j+1], y1, b1[j])); stash h1
#define L1U(j) { float z = fmaf(W1[2*(j)], y0, fmaf(W1[2*(j)+1], y1, b1[(j)])); \
  float h = ELU(z); h1_##j = h; sh[(SLOT_H1+(j))*TPB+tx] = h; }

// layer 2 unit j -> hb_u (k = 0..15 ascending), stash h2
#define L2U(u, j) { float z = b2[(j)]; \
  z = fmaf(W2[16*(j)+0],  h1_0,  z); \
  z = fmaf(W2[16*(j)+1],  h1_1,  z); \
  z = fmaf(W2[16*(j)+2],  h1_2,  z); \
  z = fmaf(W2[16*(j)+3],  h1_3,  z); \
  z = fmaf(W2[16*(j)+4],  h1_4,  z); \
  z = fmaf(W2[16*(j)+5],  h1_5,  z); \
  z = fmaf(W2[16*(j)+6],  h1_6,  z); \
  z = fmaf(W2[16*(j)+7],  h1_7,  z); \
  z = fmaf(W2[16*(j)+8],  h1_8,  z); \
  z = fmaf(W2[16*(j)+9],  h1_9,  z); \
  z = fmaf(W2[16*(j)+10], h1_10, z); \
  z = fmaf(W2[16*(j)+11], h1_11, z); \
  z = fmaf(W2[16*(j)+12], h1_12, z); \
  z = fmaf(W2[16*(j)+13], h1_13, z); \
  z = fmaf(W2[16*(j)+14], h1_14, z); \
  z = fmaf(W2[16*(j)+15], h1_15, z); \
  float h = ELU(z); hb_##u = h; sh[(SLOT_H2+(j))*TPB+tx] = h; }

#define L2BLK(jb) \
  L2U(0,(jb)*8+0) L2U(1,(jb)*8+1) L2U(2,(jb)*8+2) L2U(3,(jb)*8+3) \
  L2U(4,(jb)*8+4) L2U(5,(jb)*8+5) L2U(6,(jb)*8+6) L2U(7,(jb)*8+7)

// z3 accumulation over one 8-block (k ascending within block)
#define Z3BODY(jj, jb) \
  a = fmaf(W3[32*(jj)+(jb)*8+0], hb_0, a); \
  a = fmaf(W3[32*(jj)+(jb)*8+1], hb_1, a); \
  a = fmaf(W3[32*(jj)+(jb)*8+2], hb_2, a); \
  a = fmaf(W3[32*(jj)+(jb)*8+3], hb_3, a); \
  a = fmaf(W3[32*(jj)+(jb)*8+4], hb_4, a); \
  a = fmaf(W3[32*(jj)+(jb)*8+5], hb_5, a); \
  a = fmaf(W3[32*(jj)+(jb)*8+6], hb_6, a); \
  a = fmaf(W3[32*(jj)+(jb)*8+7], hb_7, a);
#define Z3F(jj, jb) { float a = b3[(jj)]; Z3BODY(jj, jb) z3_##jj = a; }
#define Z3N(jj, jb) { float a = z3_##jj;  Z3BODY(jj, jb) z3_##jj = a; }

// layer 3 activate unit (consumes z3_j), stash h3
#define L3U(u, j) { float h = ELU(z3_##j); hb_##u = h; \
  sh[(SLOT_H3+(j))*TPB+tx] = h; }
#define L3B0 L3U(0,0)  L3U(1,1)  L3U(2,2)  L3U(3,3)  L3U(4,4)  L3U(5,5)  L3U(6,6)  L3U(7,7)
#define L3B1 L3U(0,8)  L3U(1,9)  L3U(2,10) L3U(3,11) L3U(4,12) L3U(5,13) L3U(6,14) L3U(7,15)
#define L3B2 L3U(0,16) L3U(1,17) L3U(2,18) L3U(3,19) L3U(4,20) L3U(5,21) L3U(6,22) L3U(7,23)
#define L3B3 L3U(0,24) L3U(1,25) L3U(2,26) L3U(3,27) L3U(4,28) L3U(5,29) L3U(6,30) L3U(7,31)

#define Z4BODY(ii, jb) \
  a = fmaf(W4[32*(ii)+(jb)*8+0], hb_0, a); \
  a = fmaf(W4[32*(ii)+(jb)*8+1], hb_1, a); \
  a = fmaf(W4[32*(ii)+(jb)*8+2], hb_2, a); \
  a = fmaf(W4[32*(ii)+(jb)*8+3], hb_3, a); \
  a = fmaf(W4[32*(ii)+(jb)*8+4], hb_4, a); \
  a = fmaf(W4[32*(ii)+(jb)*8+5], hb_5, a); \
  a = fmaf(W4[32*(ii)+(jb)*8+6], hb_6, a); \
  a = fmaf(W4[32*(ii)+(jb)*8+7], hb_7, a);
#define Z4F(ii, jb) { float a = b4[(ii)]; Z4BODY(ii, jb) z4_##ii = a; }
#define Z4N(ii, jb) { float a = z4_##ii;  Z4BODY(ii, jb) z4_##ii = a; }

#define H4U(j) float h4_##j = ELU(z4_##j);
#define Z5A(k) z5 = fmaf(W5[(k)], h4_##k, z5);
#define G4U(k) float g4_##k = W5[(k)] * g5 * DFROMH(h4_##k);

// backward: a3 column-walk of W4 (j=0..15 ascending), streamed into a2
#define A2F(kk, kv) a2_##kk = W3[32*(kv)+(kk)] * g3k;
#define A2N(kk, kv) a2_##kk = fmaf(W3[32*(kv)+(kk)], g3k, a2_##kk);
#define BW3(k, A2M) { \
  float a3k = W4[(k)] * g4_0; \
  a3k = fmaf(W4[32*1+(k)],  g4_1,  a3k); \
  a3k = fmaf(W4[32*2+(k)],  g4_2,  a3k); \
  a3k = fmaf(W4[32*3+(k)],  g4_3,  a3k); \
  a3k = fmaf(W4[32*4+(k)],  g4_4,  a3k); \
  a3k = fmaf(W4[32*5+(k)],  g4_5,  a3k); \
  a3k = fmaf(W4[32*6+(k)],  g4_6,  a3k); \
  a3k = fmaf(W4[32*7+(k)],  g4_7,  a3k); \
  a3k = fmaf(W4[32*8+(k)],  g4_8,  a3k); \
  a3k = fmaf(W4[32*9+(k)],  g4_9,  a3k); \
  a3k = fmaf(W4[32*10+(k)], g4_10, a3k); \
  a3k = fmaf(W4[32*11+(k)], g4_11, a3k); \
  a3k = fmaf(W4[32*12+(k)], g4_12, a3k); \
  a3k = fmaf(W4[32*13+(k)], g4_13, a3k); \
  a3k = fmaf(W4[32*14+(k)], g4_14, a3k); \
  a3k = fmaf(W4[32*15+(k)], g4_15, a3k); \
  float h3v = sh[(SLOT_H3+(k))*TPB+tx]; \
  float g3k = a3k * DFROMH(h3v); \
  REP32_2(A2M, k) }

// g2 streamed into a1
#define A1F(kk, kv) a1_##kk = W2[16*(kv)+(kk)] * g2k;
#define A1N(kk, kv) a1_##kk = fmaf(W2[16*(kv)+(kk)], g2k, a1_##kk);
#define BW2(k, A1M) { float h2v = sh[(SLOT_H2+(k))*TPB+tx]; \
  float g2k = a2_##k * DFROMH(h2v); REP16_2(A1M, k) }

#define GYU(j) { float h1v = sh[(SLOT_H1+(j))*TPB+tx]; \
  float g1j = a1_##j * DFROMH(h1v); \
  gy0 = fmaf(W1[2*(j)],   g1j, gy0); \
  gy1 = fmaf(W1[2*(j)+1], g1j, gy1); }

__global__ __launch_bounds__(TPB, 2) void phinn_kernel(
    const float* __restrict__ x,
    const float* __restrict__ W1, const float* __restrict__ b1,
    const float* __restrict__ W2, const float* __restrict__ b2,
    const float* __restrict__ W3, const float* __restrict__ b3,
    const float* __restrict__ W4, const float* __restrict__ b4,
    const float* __restrict__ W5, const float* __restrict__ b5,
    const float* __restrict__ Wt,
    const float* __restrict__ dtp, const int* __restrict__ nstepsp,
    float* __restrict__ out) {
  __shared__ float sh[LDS_FLOATS];

  const int tx = threadIdx.x;
  const int tid = blockIdx.x * TPB + tx;   // 0 .. B*N-1
  const int bidx = tid >> 11;               // / N
  const int nidx = tid & (NN - 1);

  const float dt = dtp[0];
  const int nsteps = nstepsp[0];
  const float sqdt = sqrtf(dt);

  const float* xr = x + (size_t)bidx * ROWLEN;
  float t = xr[0];
  float y0 = xr[2 + nidx * 2 + 0];
  float y1 = xr[2 + nidx * 2 + 1];
  const float tcrit = xr[2 + NN * DD + 0];
  const float sp0 = xr[2 + NN * DD + 1];
  const float sp1 = xr[2 + NN * DD + 2];
  const float sq0 = xr[2 + NN * DD + 3];
  const float sq1 = xr[2 + NN * DD + 4];

  // Wt is (D, NSIG) row-major; tilt[d] = sum_s signals[s] * Wt[d][s]
  const float wt00 = Wt[0], wt01 = Wt[1], wt10 = Wt[2], wt11 = Wt[3];

  const uint32_t f0 = (uint32_t)(tid << 1);  // flat idx of component 0

#pragma unroll 1
  for (int i = 0; i < nsteps; ++i) {
    // per-step key: fold_in(key(42), i) = threefry((0,42), (0,i)); i uniform
    uint32_t k0, k1;
    tf2x32(0u, 42u, 0u, (uint32_t)i, k0, k1);

    float hb_0, hb_1, hb_2, hb_3, hb_4, hb_5, hb_6, hb_7;
    REP16(DH1)
    REP32(DZ3)
    REP16(DZ4)
    REP32(DA2)
    REP16(DA1)

    // ---- layer 1: 2 -> 16; stash h1 ----
    REP16(L1U)

    // ---- layer 2 (16->32) fused with z3 accumulation, 8-blocks ----
    L2BLK(0) REP32_2(Z3F, 0)
    L2BLK(1) REP32_2(Z3N, 1)
    L2BLK(2) REP32_2(Z3N, 2)
    L2BLK(3) REP32_2(Z3N, 3)

    // ---- layer 3 activate fused with z4 accumulation, 8-blocks ----
    L3B0 REP16_2(Z4F, 0)
    L3B1 REP16_2(Z4N, 1)
    L3B2 REP16_2(Z4N, 2)
    L3B3 REP16_2(Z4N, 3)

    // ---- layer 4 activate + layer 5 + softplus' + g4 ----
    REP16(H4U)
    float z5 = b5[0];
    REP16(Z5A)
    float g5 = 1.0f / (1.0f + __expf(-z5));  // d softplus = sigmoid
    REP16(G4U)

    // ---- backward: W4 column-walk streamed into a2 ----
    BW3(0, A2F)  BW3(1, A2N)  BW3(2, A2N)  BW3(3, A2N)
    BW3(4, A2N)  BW3(5, A2N)  BW3(6, A2N)  BW3(7, A2N)
    BW3(8, A2N)  BW3(9, A2N)  BW3(10, A2N) BW3(11, A2N)
    BW3(12, A2N) BW3(13, A2N) BW3(14, A2N) BW3(15, A2N)
    BW3(16, A2N) BW3(17, A2N) BW3(18, A2N) BW3(19, A2N)
    BW3(20, A2N) BW3(21, A2N) BW3(22, A2N) BW3(23, A2N)
    BW3(24, A2N) BW3(25, A2N) BW3(26, A2N) BW3(27, A2N)
    BW3(28, A2N) BW3(29, A2N) BW3(30, A2N) BW3(31, A2N)

    // ---- g2 streamed into a1 ----
    BW2(0, A1F)  BW2(1, A1N)  BW2(2, A1N)  BW2(3, A1N)
    BW2(4, A1N)  BW2(5, A1N)  BW2(6, A1N)  BW2(7, A1N)
    BW2(8, A1N)  BW2(9, A1N)  BW2(10, A1N) BW2(11, A1N)
    BW2(12, A1N) BW2(13, A1N) BW2(14, A1N) BW2(15, A1N)
    BW2(16, A1N) BW2(17, A1N) BW2(18, A1N) BW2(19, A1N)
    BW2(20, A1N) BW2(21, A1N) BW2(22, A1N) BW2(23, A1N)
    BW2(24, A1N) BW2(25, A1N) BW2(26, A1N) BW2(27, A1N)
    BW2(28, A1N) BW2(29, A1N) BW2(30, A1N) BW2(31, A1N)

    // ---- gy = W1^T (a1 * d1) ----
    float gy0 = 0.0f, gy1 = 0.0f;
    REP16(GYU)

    // ---- tilt ----
    bool pre = t < tcrit;
    float s0 = pre ? sp0 : sq0;
    float s1 = pre ? sp1 : sq1;
    float tilt0 = fmaf(s0, wt00, s1 * wt01);
    float tilt1 = fmaf(s0, wt10, s1 * wt11);

    // ---- noise (exact JAX threefry normal) ----
    float nz0 = jax_normal_elem(k0, k1, f0);
    float nz1 = jax_normal_elem(k0, k1, f0 + 1u);

    // ---- Euler-Maruyama update ----
    float drift0 = -(gy0 + tilt0);
    float drift1 = -(gy1 + tilt1);
    y0 = y0 + drift0 * dt + SIGMA_C * (nz0 * sqdt);
    y1 = y1 + drift1 * dt + SIGMA_C * (nz1 * sqdt);
    t += dt;
  }

  out[(size_t)tid * 2 + 0] = y0;
  out[(size_t)tid * 2 + 1] = y1;
}

extern "C" void kernel_launch(void* const* d_in, const int* in_sizes, int n_in,
                              void* d_out, int out_size, void* d_ws,
                              size_t ws_size, hipStream_t stream) {
  const float* x  = (const float*)d_in[0];
  const float* W1 = (const float*)d_in[1];
  const float* b1 = (const float*)d_in[2];
  const float* W2 = (const float*)d_in[3];
  const float* b2 = (const float*)d_in[4];
  const float* W3 = (const float*)d_in[5];
  const float* b3 = (const float*)d_in[6];
  const float* W4 = (const float*)d_in[7];
  const float* b4 = (const float*)d_in[8];
  const float* W5 = (const float*)d_in[9];
  const float* b5 = (const float*)d_in[10];
  const float* Wt = (const float*)d_in[11];
  const float* dt = (const float*)d_in[12];
  const int* nsteps = (const int*)d_in[13];
  float* out = (float*)d_out;

  dim3 grid((BB * NN) / TPB);
  dim3 block(TPB);
  hipLaunchKernelGGL(phinn_kernel, grid, block, 0, stream,
                     x, W1, b1, W2, b2, W3, b3, W4, b4, W5, b5, Wt, dt, nsteps,
                     out);
}